// Round 3
// baseline (263.567 us; speedup 1.0000x reference)
//
#include <hip/hip_runtime.h>
#include <hip/hip_bf16.h>
#include <hip/hip_fp16.h>
#include <math.h>

#define HH 128
#define WW 128
#define HWSZ (HH*WW)
#define CH 64
#define OC 64
#define NB 8
#define RG 28            // staged region dim: 8 + 2*10 halo
#define RPX (RG*RG)      // 784

// ws layout: xT fp16 [b][h][w][c]   (8*16384*64*2 = 16777216 B)
//            offs float4 [b][p]     (2097152 B)
//            wmT2 fp16 [k][oc][ch]  (36864*2 B)
#define XT_BYTES   (16777216u)   // R8 bug: was 8388608 -> offs/wmT2 aliased xT -> NaN
#define OFFS_BYTES (2097152u)
// d_out (33.5 MB) doubles as scratch for the 8 offset partials (16.8 MB)

typedef _Float16 f16x8 __attribute__((ext_vector_type(8)));   // 4 VGPRs
typedef __attribute__((ext_vector_type(4))) float f32x4_t;    // 4 fp32 acc

// ---------------- Kernel P: fused transpose + offsets-partials + wmT2 ----------------
// blocks [0,4096): offsets partials (8 ch x 2 rows, no atomics)
// blocks [4096,6144): x NCHW fp32 -> xT NHWC fp16
// blocks [6144,6153): w_main -> wmT2 [k][oc][ch] fp16
__global__ __launch_bounds__(256) void pre_kernel(
    const float* __restrict__ x, const float* __restrict__ w_main,
    const float* __restrict__ w_rot, const float* __restrict__ w_str,
    const float* __restrict__ w_whl,
    __half* __restrict__ xT, __half* __restrict__ wmT2,
    float4* __restrict__ part)
{
    __shared__ float shmem[64 * 65];     // 16.6 KB, reused by both branches
    const int t = threadIdx.x;
    const int i = blockIdx.x;

    if (i >= 6144) {                     // ---- wmT2 tail ----
        const int base = (i - 6144) * 4096 + t * 16;
        #pragma unroll
        for (int j = 0; j < 16; ++j) {
            const int e = base + j;
            const int k = e >> 12;
            const int r = e & 4095;
            const int o = r >> 6;
            const int c = r & 63;
            wmT2[e] = __float2half(w_main[(size_t)o * (CH * 9) + c * 9 + k]);
        }
        return;
    }

    if (i >= 4096) {                     // ---- transpose ----
        float (*tile)[65] = (float(*)[65])shmem;
        const int it = i - 4096;
        const int b = it & 7;            // XCD-affine
        const int j = it >> 3;
        const int h  = j >> 1;
        const int w0 = (j & 1) * 64;
        const float* xb = x + (size_t)b * CH * HWSZ + h * WW + w0;
        {
            const int w = t & 63, c0 = (t >> 6) * 16;
            #pragma unroll
            for (int jj = 0; jj < 16; ++jj)
                tile[c0 + jj][w] = xb[(size_t)(c0 + jj) * HWSZ + w];
        }
        __syncthreads();
        {
            const int c = t & 63, wq = t >> 6;
            __half* o = xT + ((size_t)b * HWSZ + h * WW + w0) * 64;
            #pragma unroll
            for (int jj = 0; jj < 16; ++jj) {
                const int w = wq * 16 + jj;
                o[(size_t)w * 64 + c] = __float2half(tile[c][w]);
            }
        }
        return;
    }

    // ---- offsets partials ----
    float (*xs)[4][WW] = (float(*)[4][WW])shmem;   // [8][4][128]
    const int b  = i & 7;            // XCD-affine
    const int rp = (i >> 3) & 63;
    const int cg = i >> 9;           // 0..7
    const int h0 = rp * 2;
    const int c0 = cg * 8;
    const float* xb = x + (size_t)b * CH * HWSZ;
    #pragma unroll
    for (int jj = 0; jj < 4; ++jj) {
        const int u   = t + jj * 256;
        const int ch  = u >> 7;
        const int rem = u & 127;
        const int row = rem >> 5;
        const int w4  = (rem & 31) * 4;
        const int grow = h0 - 1 + row;
        float4 v = make_float4(0.f, 0.f, 0.f, 0.f);
        if (grow >= 0 && grow < HH)
            v = *(const float4*)&xb[((size_t)(c0 + ch) * HH + grow) * WW + w4];
        *(float4*)&xs[ch][row][w4] = v;
    }
    __syncthreads();
    const int r = t >> 7, w = t & 127;
    const int wl = max(w - 1, 0), wr2 = min(w + 1, WW - 1);
    const float ml = (w > 0) ? 1.f : 0.f, mr = (w < WW - 1) ? 1.f : 0.f;
    float a0 = 0.f, a1 = 0.f, a2 = 0.f, a3 = 0.f;
    #pragma unroll
    for (int ch = 0; ch < 8; ++ch) {
        const int cc = c0 + ch;
        #pragma unroll
        for (int dy = 0; dy < 3; ++dy) {
            const float* row_ = &xs[ch][r + dy][0];
            const float nl = row_[wl] * ml;
            const float nc = row_[w];
            const float nr = row_[wr2] * mr;
            const int d0 = cc * 9 + dy * 3;
            a0 = fmaf(nl, w_rot[d0 + 0], a0); a0 = fmaf(nc, w_rot[d0 + 1], a0); a0 = fmaf(nr, w_rot[d0 + 2], a0);
            a1 = fmaf(nl, w_rot[576 + d0 + 0], a1); a1 = fmaf(nc, w_rot[576 + d0 + 1], a1); a1 = fmaf(nr, w_rot[576 + d0 + 2], a1);
            a2 = fmaf(nl, w_str[d0 + 0], a2); a2 = fmaf(nc, w_str[d0 + 1], a2); a2 = fmaf(nr, w_str[d0 + 2], a2);
            a3 = fmaf(nl, w_whl[d0 + 0], a3); a3 = fmaf(nc, w_whl[d0 + 1], a3); a3 = fmaf(nr, w_whl[d0 + 2], a3);
        }
    }
    part[((size_t)cg * NB + b) * HWSZ + (h0 + r) * WW + w] = make_float4(a0, a1, a2, a3);
}

// ---------------- Kernel R: reduce partials -> final offs (sin,cos,wr*r,wr) ----------------
__global__ __launch_bounds__(256) void reduce_kernel(
    const float4* __restrict__ part,
    const float* __restrict__ b_rot, const float* __restrict__ b_str,
    const float* __restrict__ b_whl, float4* __restrict__ offs)
{
    const int i = blockIdx.x * 256 + threadIdx.x;   // < NB*HWSZ
    float4 s = make_float4(0.f, 0.f, 0.f, 0.f);
    #pragma unroll
    for (int cg = 0; cg < 8; ++cg) {
        const float4 p = part[(size_t)cg * NB * HWSZ + i];
        s.x += p.x; s.y += p.y; s.z += p.z; s.w += p.w;
    }
    float sv = s.x + b_rot[0], cv = s.y + b_rot[1];
    const float inv = 1.0f / sqrtf(sv * sv + cv * cv + 1e-6f);
    const float rr = tanhf(s.z + b_str[0]) * 1.25f + 1.75f;   // A,B
    const float wq = tanhf(s.w + b_whl[0]) * 1.0f + 2.0f;     // C,D
    offs[i] = make_float4(sv * inv, cv * inv, wq * rr, wq);
}

// ---------------- Kernel B: LDS-staged gather (bijective swizzle) + MFMA ----------------
// Swizzle: 16B-slot(p,q) = (4p + (q ^ ((p>>1)&3))) mod 8 is a bijection over
// all 8 slots per 128B line (old (q^(p&3)) hit only 4 -> 4-way conflicts).
// g0 staging loads issued BEFORE the geometry preamble (latency hidden);
// B-fragments software-pipelined one tap ahead; LDS gather indices
// precomputed once (group-invariant).
__global__ __launch_bounds__(256, 3) void deform_kernel(
    const __half* __restrict__ xT, const __half* __restrict__ wmT2,
    const float4* __restrict__ offs, float* __restrict__ out)
{
    __shared__ union {
        uint4 xs[RPX * 4];      // 784 px * 64 B (32 ch fp16) = 50176 B
        float ots[64][67];      // epilogue
    } sh;
    const int t  = threadIdx.x;
    const int wv = t >> 6;
    const int l  = t & 63;
    const int lm = l & 15;          // A-row (px) / B oc
    const int lg = l >> 4;          // 8-channel slab within group
    const int i  = blockIdx.x;      // 2048 blocks
    const int b  = i & 7;           // XCD-affine
    const int tile = i >> 3;        // 0..255
    const int w0 = (tile & 15) * 8;
    const int h0 = (tile >> 4) * 8;
    const int pi = wv * 16 + lm;    // local px 0..63
    const int h = h0 + (pi >> 3);
    const int w = w0 + (pi & 7);
    const __half* xb = xT + (size_t)b * HWSZ * 64;

    // A) issue g0 staging loads early; hold in regs across the preamble
    uint4 st[13];
    #pragma unroll
    for (int j = 0; j < 13; ++j) {
        const int u = t + j * 256;
        if (u < RPX * 4) {
            const int pxu = u >> 2, q = u & 3;
            const int lr = pxu / RG;
            const int lc = pxu - lr * RG;
            const int gy = min(max(h0 - 10 + lr, 0), HH - 1);
            const int gx = min(max(w0 - 10 + lc, 0), WW - 1);
            st[j] = *(const uint4*)(xb + (size_t)(gy * WW + gx) * 64 + q * 8);
        }
    }

    // B) geometry preamble (runs while g0 loads are in flight)
    const float4 o4 = offs[(size_t)b * HWSZ + h * WW + w];
    const float sv = o4.x, cv = o4.y, av = o4.z, wvl = o4.w;
    const float hh  = (float)h;
    const float wwf = (float)w;

    int idx00[9], idx01[9], idx10[9], idx11[9];   // swizzled LDS quad indices
    __half2 w2[9][4];
    #pragma unroll
    for (int k = 0; k < 9; ++k) {
        const float kyf = (float)(k / 3) - 1.f;
        const float kxf = (float)(k % 3) - 1.f;
        const float o0v = kyf * av;
        const float o1v = kxf * wvl;
        const float pyf = hh  + cv * o0v + sv * o1v;
        const float pxf = wwf - sv * o0v + cv * o1v;
        const float y0f = floorf(pyf), x0f = floorf(pxf);
        const float ly = pyf - y0f, lx = pxf - x0f;
        const int y0 = (int)y0f, x0i = (int)x0f;
        const int y1 = y0 + 1, x1 = x0i + 1;
        const bool vy0 = (y0 >= 0) && (y0 < HH);
        const bool vy1 = (y1 >= 0) && (y1 < HH);
        const bool vx0 = (x0i >= 0) && (x0i < WW);
        const bool vx1 = (x1 >= 0) && (x1 < WW);
        w2[k][0] = __float2half2_rn((1.f - ly) * (1.f - lx) * ((vy0 && vx0) ? 1.f : 0.f));
        w2[k][1] = __float2half2_rn((1.f - ly) * lx         * ((vy0 && vx1) ? 1.f : 0.f));
        w2[k][2] = __float2half2_rn(ly * (1.f - lx)         * ((vy1 && vx0) ? 1.f : 0.f));
        w2[k][3] = __float2half2_rn(ly * lx                 * ((vy1 && vx1) ? 1.f : 0.f));
        const int iy0 = min(max(y0, 0), HH - 1), iy1 = min(max(y1, 0), HH - 1);
        const int ix0 = min(max(x0i, 0), WW - 1), ix1 = min(max(x1, 0), WW - 1);
        const int dyy = iy1 - iy0, dxx = ix1 - ix0;
        const int p00 = (iy0 - (h0 - 10)) * RG + (ix0 - (w0 - 10));
        const int p01 = p00 + dxx;
        const int p10 = p00 + dyy * RG;
        const int p11 = p10 + dxx;
        idx00[k] = p00 * 4 + (lg ^ ((p00 >> 1) & 3));
        idx01[k] = p01 * 4 + (lg ^ ((p01 >> 1) & 3));
        idx10[k] = p10 * 4 + (lg ^ ((p10 >> 1) & 3));
        idx11[k] = p11 * 4 + (lg ^ ((p11 >> 1) & 3));
    }

    // C) write g0 into LDS (bijective slots)
    #pragma unroll
    for (int j = 0; j < 13; ++j) {
        const int u = t + j * 256;
        if (u < RPX * 4) {
            const int pxu = u >> 2, q = u & 3;
            sh.xs[pxu * 4 + (q ^ ((pxu >> 1) & 3))] = st[j];
        }
    }

    f32x4_t acc0 = {0.f, 0.f, 0.f, 0.f};
    f32x4_t acc1 = acc0, acc2 = acc0, acc3 = acc0;

    auto compute = [&](int g) {
        const int cb0 = g * 32 + lg * 8;
        const __half* wb = wmT2 + lm * 64 + cb0;
        f16x8 bc0 = *(const f16x8*)(wb);
        f16x8 bc1 = *(const f16x8*)(wb + 1024);
        f16x8 bc2 = *(const f16x8*)(wb + 2048);
        f16x8 bc3 = *(const f16x8*)(wb + 3072);
        #pragma unroll
        for (int k = 0; k < 9; ++k) {
            f16x8 bn0, bn1, bn2, bn3;
            if (k < 8) {                       // prefetch next tap's B frags
                const __half* wp = wb + (size_t)(k + 1) * 4096;
                bn0 = *(const f16x8*)(wp);
                bn1 = *(const f16x8*)(wp + 1024);
                bn2 = *(const f16x8*)(wp + 2048);
                bn3 = *(const f16x8*)(wp + 3072);
            }
            union Q { uint4 q; __half2 h2[4]; };
            Q q00, q01, q10, q11;
            q00.q = sh.xs[idx00[k]];
            q01.q = sh.xs[idx01[k]];
            q10.q = sh.xs[idx10[k]];
            q11.q = sh.xs[idx11[k]];
            union { __half2 h2[4]; f16x8 v; } af;
            #pragma unroll
            for (int j = 0; j < 4; ++j) {      // depth-2 blend tree
                const __half2 e0 = __hfma2(q00.h2[j], w2[k][0], __hmul2(q01.h2[j], w2[k][1]));
                const __half2 e1 = __hfma2(q10.h2[j], w2[k][2], __hmul2(q11.h2[j], w2[k][3]));
                af.h2[j] = __hadd2(e0, e1);
            }
            acc0 = __builtin_amdgcn_mfma_f32_16x16x32_f16(af.v, bc0, acc0, 0, 0, 0);
            acc1 = __builtin_amdgcn_mfma_f32_16x16x32_f16(af.v, bc1, acc1, 0, 0, 0);
            acc2 = __builtin_amdgcn_mfma_f32_16x16x32_f16(af.v, bc2, acc2, 0, 0, 0);
            acc3 = __builtin_amdgcn_mfma_f32_16x16x32_f16(af.v, bc3, acc3, 0, 0, 0);
            if (k < 8) { bc0 = bn0; bc1 = bn1; bc2 = bn2; bc3 = bn3; }
        }
    };

    __syncthreads();
    compute(0);
    __syncthreads();
    // stage g1 (channels 32..63), same bijective slots, same indices
    for (int u = t; u < RPX * 4; u += 256) {
        const int pxu = u >> 2, q = u & 3;
        const int lr = pxu / RG;
        const int lc = pxu - lr * RG;
        const int gy = min(max(h0 - 10 + lr, 0), HH - 1);
        const int gx = min(max(w0 - 10 + lc, 0), WW - 1);
        sh.xs[pxu * 4 + (q ^ ((pxu >> 1) & 3))] =
            *(const uint4*)(xb + (size_t)(gy * WW + gx) * 64 + 32 + q * 8);
    }
    __syncthreads();
    compute(1);

    __syncthreads();
    // epilogue: C/D layout col=lane&15 (oc), row=(lane>>4)*4+reg (local px)
    const int pxw = wv * 16 + lg * 4;
    #pragma unroll
    for (int rg2 = 0; rg2 < 4; ++rg2) {
        sh.ots[pxw + rg2][ 0 + lm] = acc0[rg2];
        sh.ots[pxw + rg2][16 + lm] = acc1[rg2];
        sh.ots[pxw + rg2][32 + lm] = acc2[rg2];
        sh.ots[pxw + rg2][48 + lm] = acc3[rg2];
    }
    __syncthreads();
    const int oo = t >> 2;
    const int q  = (t & 3) * 16;
    #pragma unroll
    for (int j2 = 0; j2 < 4; ++j2) {
        const int px = q + j2 * 4;
        float4 v = make_float4(sh.ots[px + 0][oo], sh.ots[px + 1][oo],
                               sh.ots[px + 2][oo], sh.ots[px + 3][oo]);
        *(float4*)&out[((size_t)b * OC + oo) * HWSZ +
                       (h0 + (px >> 3)) * WW + w0 + (px & 7)] = v;
    }
}

extern "C" void kernel_launch(void* const* d_in, const int* in_sizes, int n_in,
                              void* d_out, int out_size, void* d_ws, size_t ws_size,
                              hipStream_t stream)
{
    const float* x      = (const float*)d_in[0];
    const float* w_main = (const float*)d_in[1];
    const float* w_rot  = (const float*)d_in[2];
    const float* b_rot  = (const float*)d_in[3];
    const float* w_str  = (const float*)d_in[4];
    const float* b_str  = (const float*)d_in[5];
    const float* w_whl  = (const float*)d_in[6];
    const float* b_whl  = (const float*)d_in[7];
    float* out = (float*)d_out;

    char* ws = (char*)d_ws;
    __half*  xT   = (__half*)ws;
    float4*  offs = (float4*)(ws + XT_BYTES);
    __half*  wmT2 = (__half*)(ws + XT_BYTES + OFFS_BYTES);
    float4*  part = (float4*)d_out;   // 16.8 MB partial scratch inside 33.5 MB out

    pre_kernel<<<dim3(6153), 256, 0, stream>>>(x, w_main, w_rot, w_str, w_whl,
                                               xT, wmT2, part);
    reduce_kernel<<<dim3(NB * HWSZ / 256), 256, 0, stream>>>(
        part, b_rot, b_str, b_whl, offs);
    deform_kernel<<<dim3(2048), 256, 0, stream>>>(xT, wmT2, offs, out);
}

// Round 4
// 205.323 us; speedup vs baseline: 1.2837x; 1.2837x over previous
//
#include <hip/hip_runtime.h>
#include <hip/hip_bf16.h>
#include <hip/hip_fp16.h>
#include <math.h>

#define HH 128
#define WW 128
#define HWSZ (HH*WW)
#define CH 64
#define OC 64
#define NB 8
#define RG 28            // staged region dim: 8 + 2*10 halo
#define RPX (RG*RG)      // 784

// ws layout: xT fp16 [b][h][w][c]   (8*16384*64*2 = 16777216 B)
//            offs float4 [b][p]     (2097152 B)
//            wmT2 fp16 [k][oc][ch]  (36864*2 B)
#define XT_BYTES   (16777216u)   // R8 bug: was 8388608 -> offs/wmT2 aliased xT -> NaN
#define OFFS_BYTES (2097152u)
// d_out (33.5 MB) doubles as scratch for the 8 offset partials (16.8 MB)

typedef _Float16 f16x8 __attribute__((ext_vector_type(8)));   // 4 VGPRs
typedef __attribute__((ext_vector_type(4))) float f32x4_t;    // 4 fp32 acc

// ---------------- Kernel P: fused transpose + offsets-partials + wmT2 ----------------
// blocks [0,4096): offsets partials (8 ch x 2 rows, no atomics)
// blocks [4096,6144): x NCHW fp32 -> xT NHWC fp16
// blocks [6144,6153): w_main -> wmT2 [k][oc][ch] fp16
__global__ __launch_bounds__(256) void pre_kernel(
    const float* __restrict__ x, const float* __restrict__ w_main,
    const float* __restrict__ w_rot, const float* __restrict__ w_str,
    const float* __restrict__ w_whl,
    __half* __restrict__ xT, __half* __restrict__ wmT2,
    float4* __restrict__ part)
{
    __shared__ float shmem[64 * 65];     // 16.6 KB, reused by both branches
    const int t = threadIdx.x;
    const int i = blockIdx.x;

    if (i >= 6144) {                     // ---- wmT2 tail ----
        const int base = (i - 6144) * 4096 + t * 16;
        #pragma unroll
        for (int j = 0; j < 16; ++j) {
            const int e = base + j;
            const int k = e >> 12;
            const int r = e & 4095;
            const int o = r >> 6;
            const int c = r & 63;
            wmT2[e] = __float2half(w_main[(size_t)o * (CH * 9) + c * 9 + k]);
        }
        return;
    }

    if (i >= 4096) {                     // ---- transpose ----
        float (*tile)[65] = (float(*)[65])shmem;
        const int it = i - 4096;
        const int b = it & 7;            // XCD-affine
        const int j = it >> 3;
        const int h  = j >> 1;
        const int w0 = (j & 1) * 64;
        const float* xb = x + (size_t)b * CH * HWSZ + h * WW + w0;
        {
            const int w = t & 63, c0 = (t >> 6) * 16;
            #pragma unroll
            for (int jj = 0; jj < 16; ++jj)
                tile[c0 + jj][w] = xb[(size_t)(c0 + jj) * HWSZ + w];
        }
        __syncthreads();
        {
            const int c = t & 63, wq = t >> 6;
            __half* o = xT + ((size_t)b * HWSZ + h * WW + w0) * 64;
            #pragma unroll
            for (int jj = 0; jj < 16; ++jj) {
                const int w = wq * 16 + jj;
                o[(size_t)w * 64 + c] = __float2half(tile[c][w]);
            }
        }
        return;
    }

    // ---- offsets partials ----
    float (*xs)[4][WW] = (float(*)[4][WW])shmem;   // [8][4][128]
    const int b  = i & 7;            // XCD-affine
    const int rp = (i >> 3) & 63;
    const int cg = i >> 9;           // 0..7
    const int h0 = rp * 2;
    const int c0 = cg * 8;
    const float* xb = x + (size_t)b * CH * HWSZ;
    #pragma unroll
    for (int jj = 0; jj < 4; ++jj) {
        const int u   = t + jj * 256;
        const int ch  = u >> 7;
        const int rem = u & 127;
        const int row = rem >> 5;
        const int w4  = (rem & 31) * 4;
        const int grow = h0 - 1 + row;
        float4 v = make_float4(0.f, 0.f, 0.f, 0.f);
        if (grow >= 0 && grow < HH)
            v = *(const float4*)&xb[((size_t)(c0 + ch) * HH + grow) * WW + w4];
        *(float4*)&xs[ch][row][w4] = v;
    }
    __syncthreads();
    const int r = t >> 7, w = t & 127;
    const int wl = max(w - 1, 0), wr2 = min(w + 1, WW - 1);
    const float ml = (w > 0) ? 1.f : 0.f, mr = (w < WW - 1) ? 1.f : 0.f;
    float a0 = 0.f, a1 = 0.f, a2 = 0.f, a3 = 0.f;
    #pragma unroll
    for (int ch = 0; ch < 8; ++ch) {
        const int cc = c0 + ch;
        #pragma unroll
        for (int dy = 0; dy < 3; ++dy) {
            const float* row_ = &xs[ch][r + dy][0];
            const float nl = row_[wl] * ml;
            const float nc = row_[w];
            const float nr = row_[wr2] * mr;
            const int d0 = cc * 9 + dy * 3;
            a0 = fmaf(nl, w_rot[d0 + 0], a0); a0 = fmaf(nc, w_rot[d0 + 1], a0); a0 = fmaf(nr, w_rot[d0 + 2], a0);
            a1 = fmaf(nl, w_rot[576 + d0 + 0], a1); a1 = fmaf(nc, w_rot[576 + d0 + 1], a1); a1 = fmaf(nr, w_rot[576 + d0 + 2], a1);
            a2 = fmaf(nl, w_str[d0 + 0], a2); a2 = fmaf(nc, w_str[d0 + 1], a2); a2 = fmaf(nr, w_str[d0 + 2], a2);
            a3 = fmaf(nl, w_whl[d0 + 0], a3); a3 = fmaf(nc, w_whl[d0 + 1], a3); a3 = fmaf(nr, w_whl[d0 + 2], a3);
        }
    }
    part[((size_t)cg * NB + b) * HWSZ + (h0 + r) * WW + w] = make_float4(a0, a1, a2, a3);
}

// ---------------- Kernel R: reduce partials -> final offs (sin,cos,wr*r,wr) ----------------
__global__ __launch_bounds__(256) void reduce_kernel(
    const float4* __restrict__ part,
    const float* __restrict__ b_rot, const float* __restrict__ b_str,
    const float* __restrict__ b_whl, float4* __restrict__ offs)
{
    const int i = blockIdx.x * 256 + threadIdx.x;   // < NB*HWSZ
    float4 s = make_float4(0.f, 0.f, 0.f, 0.f);
    #pragma unroll
    for (int cg = 0; cg < 8; ++cg) {
        const float4 p = part[(size_t)cg * NB * HWSZ + i];
        s.x += p.x; s.y += p.y; s.z += p.z; s.w += p.w;
    }
    float sv = s.x + b_rot[0], cv = s.y + b_rot[1];
    const float inv = 1.0f / sqrtf(sv * sv + cv * cv + 1e-6f);
    const float rr = tanhf(s.z + b_str[0]) * 1.25f + 1.75f;   // A,B
    const float wq = tanhf(s.w + b_whl[0]) * 1.0f + 2.0f;     // C,D
    offs[i] = make_float4(sv * inv, cv * inv, wq * rr, wq);
}

// ---------------- Kernel B: LDS-staged gather + MFMA (R0 structure) ----------------
// R0 skeleton (84 VGPR, no spills) + two validated deltas only:
//   (a) bijective quad swizzle: slot(p,q) = q ^ ((p>>1)&3)  ->  (4p + slot) mod 8
//       covers all 8 16B-slots (old q^(p&3) hit 4 -> 4-way conflicts; R3 measured
//       conflicts 6.67M -> 4.55M with this fix)
//   (b) one-tap-ahead B-fragment prefetch (transient 16 VGPRs, no held arrays —
//       R3's regression was st[13] held across the preamble spilling to scratch)
__global__ __launch_bounds__(256, 3) void deform_kernel(
    const __half* __restrict__ xT, const __half* __restrict__ wmT2,
    const float4* __restrict__ offs, float* __restrict__ out)
{
    __shared__ union {
        uint4 xs[RPX * 4];      // 784 px * 64 B (32 ch fp16) = 50176 B
        float ots[64][67];      // epilogue
    } sh;
    const int t  = threadIdx.x;
    const int wv = t >> 6;
    const int l  = t & 63;
    const int lm = l & 15;          // A-row (px) / B oc
    const int lg = l >> 4;          // 8-channel slab within group
    const int i  = blockIdx.x;      // 2048 blocks
    const int b  = i & 7;           // XCD-affine
    const int tile = i >> 3;        // 0..255
    const int w0 = (tile & 15) * 8;
    const int h0 = (tile >> 4) * 8;
    const int pi = wv * 16 + lm;    // local px 0..63
    const int h = h0 + (pi >> 3);
    const int w = w0 + (pi & 7);
    const float4 o4 = offs[(size_t)b * HWSZ + h * WW + w];
    const float sv = o4.x, cv = o4.y, av = o4.z, wvl = o4.w;
    const float hh  = (float)h;
    const float wwf = (float)w;
    const __half* xb = xT + (size_t)b * HWSZ * 64;

    // per-tap geometry hoisted: region index, step-pack, 4 broadcast half2 weights
    int ti[9], td[9];
    __half2 w2[9][4];
    #pragma unroll
    for (int k = 0; k < 9; ++k) {
        const float kyf = (float)(k / 3) - 1.f;
        const float kxf = (float)(k % 3) - 1.f;
        const float o0v = kyf * av;
        const float o1v = kxf * wvl;
        const float pyf = hh  + cv * o0v + sv * o1v;
        const float pxf = wwf - sv * o0v + cv * o1v;
        const float y0f = floorf(pyf), x0f = floorf(pxf);
        const float ly = pyf - y0f, lx = pxf - x0f;
        const int y0 = (int)y0f, x0i = (int)x0f;
        const int y1 = y0 + 1, x1 = x0i + 1;
        const bool vy0 = (y0 >= 0) && (y0 < HH);
        const bool vy1 = (y1 >= 0) && (y1 < HH);
        const bool vx0 = (x0i >= 0) && (x0i < WW);
        const bool vx1 = (x1 >= 0) && (x1 < WW);
        w2[k][0] = __float2half2_rn((1.f - ly) * (1.f - lx) * ((vy0 && vx0) ? 1.f : 0.f));
        w2[k][1] = __float2half2_rn((1.f - ly) * lx         * ((vy0 && vx1) ? 1.f : 0.f));
        w2[k][2] = __float2half2_rn(ly * (1.f - lx)         * ((vy1 && vx0) ? 1.f : 0.f));
        w2[k][3] = __float2half2_rn(ly * lx                 * ((vy1 && vx1) ? 1.f : 0.f));
        const int iy0 = min(max(y0, 0), HH - 1), iy1 = min(max(y1, 0), HH - 1);
        const int ix0 = min(max(x0i, 0), WW - 1), ix1 = min(max(x1, 0), WW - 1);
        ti[k] = (iy0 - (h0 - 10)) * RG + (ix0 - (w0 - 10));
        td[k] = (ix1 - ix0) | ((iy1 - iy0) << 1);
    }

    f32x4_t acc0 = {0.f, 0.f, 0.f, 0.f};
    f32x4_t acc1 = acc0, acc2 = acc0, acc3 = acc0;

    auto compute = [&](int g) {
        const int cb0 = g * 32 + lg * 8;
        const __half* wb = wmT2 + lm * 64 + cb0;
        f16x8 bc0 = *(const f16x8*)(wb);
        f16x8 bc1 = *(const f16x8*)(wb + 1024);
        f16x8 bc2 = *(const f16x8*)(wb + 2048);
        f16x8 bc3 = *(const f16x8*)(wb + 3072);
        #pragma unroll
        for (int k = 0; k < 9; ++k) {
            f16x8 bn0, bn1, bn2, bn3;
            if (k < 8) {                       // prefetch next tap's B frags
                const __half* wp = wb + (size_t)(k + 1) * 4096;
                bn0 = *(const f16x8*)(wp);
                bn1 = *(const f16x8*)(wp + 1024);
                bn2 = *(const f16x8*)(wp + 2048);
                bn3 = *(const f16x8*)(wp + 3072);
            }
            const int i00 = ti[k];
            const int dxx = td[k] & 1;
            const int dyy = (td[k] >> 1) * RG;
            const int i01 = i00 + dxx;
            const int i10 = i00 + dyy;
            const int i11 = i10 + dxx;
            union Q { uint4 q; __half2 h2[4]; };
            Q q00, q01, q10, q11;
            q00.q = sh.xs[i00 * 4 + (lg ^ ((i00 >> 1) & 3))];
            q01.q = sh.xs[i01 * 4 + (lg ^ ((i01 >> 1) & 3))];
            q10.q = sh.xs[i10 * 4 + (lg ^ ((i10 >> 1) & 3))];
            q11.q = sh.xs[i11 * 4 + (lg ^ ((i11 >> 1) & 3))];
            union { __half2 h2[4]; f16x8 v; } af;
            #pragma unroll
            for (int j = 0; j < 4; ++j) {      // depth-2 blend tree
                const __half2 e0 = __hfma2(q00.h2[j], w2[k][0], __hmul2(q01.h2[j], w2[k][1]));
                const __half2 e1 = __hfma2(q10.h2[j], w2[k][2], __hmul2(q11.h2[j], w2[k][3]));
                af.h2[j] = __hadd2(e0, e1);
            }
            acc0 = __builtin_amdgcn_mfma_f32_16x16x32_f16(af.v, bc0, acc0, 0, 0, 0);
            acc1 = __builtin_amdgcn_mfma_f32_16x16x32_f16(af.v, bc1, acc1, 0, 0, 0);
            acc2 = __builtin_amdgcn_mfma_f32_16x16x32_f16(af.v, bc2, acc2, 0, 0, 0);
            acc3 = __builtin_amdgcn_mfma_f32_16x16x32_f16(af.v, bc3, acc3, 0, 0, 0);
            if (k < 8) { bc0 = bn0; bc1 = bn1; bc2 = bn2; bc3 = bn3; }
        }
    };

    for (int g = 0; g < 2; ++g) {
        __syncthreads();
        // stage 28x28 region, 32 ch of group g (64 B/px), bijective swizzled slots
        for (int u = t; u < RPX * 4; u += 256) {
            const int pxu = u >> 2, q = u & 3;
            const int lr = pxu / RG;
            const int lc = pxu - lr * RG;
            const int gy = min(max(h0 - 10 + lr, 0), HH - 1);
            const int gx = min(max(w0 - 10 + lc, 0), WW - 1);
            sh.xs[pxu * 4 + (q ^ ((pxu >> 1) & 3))] =
                *(const uint4*)(xb + (size_t)(gy * WW + gx) * 64 + g * 32 + q * 8);
        }
        __syncthreads();
        compute(g);
    }

    __syncthreads();
    // epilogue: C/D layout col=lane&15 (oc), row=(lane>>4)*4+reg (local px)
    const int pxw = wv * 16 + lg * 4;
    #pragma unroll
    for (int rg2 = 0; rg2 < 4; ++rg2) {
        sh.ots[pxw + rg2][ 0 + lm] = acc0[rg2];
        sh.ots[pxw + rg2][16 + lm] = acc1[rg2];
        sh.ots[pxw + rg2][32 + lm] = acc2[rg2];
        sh.ots[pxw + rg2][48 + lm] = acc3[rg2];
    }
    __syncthreads();
    const int oo = t >> 2;
    const int q  = (t & 3) * 16;
    #pragma unroll
    for (int j2 = 0; j2 < 4; ++j2) {
        const int px = q + j2 * 4;
        float4 v = make_float4(sh.ots[px + 0][oo], sh.ots[px + 1][oo],
                               sh.ots[px + 2][oo], sh.ots[px + 3][oo]);
        *(float4*)&out[((size_t)b * OC + oo) * HWSZ +
                       (h0 + (px >> 3)) * WW + w0 + (px & 7)] = v;
    }
}

extern "C" void kernel_launch(void* const* d_in, const int* in_sizes, int n_in,
                              void* d_out, int out_size, void* d_ws, size_t ws_size,
                              hipStream_t stream)
{
    const float* x      = (const float*)d_in[0];
    const float* w_main = (const float*)d_in[1];
    const float* w_rot  = (const float*)d_in[2];
    const float* b_rot  = (const float*)d_in[3];
    const float* w_str  = (const float*)d_in[4];
    const float* b_str  = (const float*)d_in[5];
    const float* w_whl  = (const float*)d_in[6];
    const float* b_whl  = (const float*)d_in[7];
    float* out = (float*)d_out;

    char* ws = (char*)d_ws;
    __half*  xT   = (__half*)ws;
    float4*  offs = (float4*)(ws + XT_BYTES);
    __half*  wmT2 = (__half*)(ws + XT_BYTES + OFFS_BYTES);
    float4*  part = (float4*)d_out;   // 16.8 MB partial scratch inside 33.5 MB out

    pre_kernel<<<dim3(6153), 256, 0, stream>>>(x, w_main, w_rot, w_str, w_whl,
                                               xT, wmT2, part);
    reduce_kernel<<<dim3(NB * HWSZ / 256), 256, 0, stream>>>(
        part, b_rot, b_str, b_whl, offs);
    deform_kernel<<<dim3(2048), 256, 0, stream>>>(xT, wmT2, offs, out);
}